// Round 1
// baseline (195.719 us; speedup 1.0000x reference)
//
#include <hip/hip_runtime.h>
#include <hip/hip_bf16.h>
#include <stdint.h>

#define NPTS 2048
#define DM 256
#define NH 4
#define DH 64
#define KK 1024

// ws layout (floats): Q[4][2048][64] | K[4][2048][64] | V[4][2048][64]
#define HEAD_STRIDE (NPTS*DH)     // 131072
#define MAT_STRIDE  (NH*NPTS*DH)  // 524288

// ---------------- Kernel 1: projections + rotary ----------------
// grid (256, 3), block 256. z: 0=Q(rotary+scale), 1=K(rotary), 2=V
__global__ __launch_bounds__(256) void proj_rope_kernel(
    const float* __restrict__ xq, const float* __restrict__ xk, const float* __restrict__ xv,
    const float* __restrict__ emb,
    const float* __restrict__ Wq, const float* __restrict__ bq,
    const float* __restrict__ Wk, const float* __restrict__ bk,
    const float* __restrict__ Wv, const float* __restrict__ bv,
    float* __restrict__ ws)
{
    const int z = blockIdx.y;
    const int n0 = blockIdx.x * 8;
    const float* X = (z==0) ? xq : (z==1) ? xk : xv;
    const float* W = (z==0) ? Wq : (z==1) ? Wk : Wv;
    const float* B = (z==0) ? bq : (z==1) ? bk : bv;

    __shared__ float s_in[8][DM];
    {
        const float4* X4 = (const float4*)(X + (size_t)n0 * DM);
        float4* s4 = (float4*)&s_in[0][0];
        #pragma unroll
        for (int i = 0; i < 2; i++) {
            int f = threadIdx.x + 256*i;
            s4[f] = X4[f];
        }
    }
    __syncthreads();

    const int c = threadIdx.x;
    const int h = c >> 6, d = c & 63;
    const float bias = B[c];
    float acc[8];
    #pragma unroll
    for (int r = 0; r < 8; r++) acc[r] = bias;

    const float4* W4 = (const float4*)(W + (size_t)c * DM);
    #pragma unroll 4
    for (int k4 = 0; k4 < DM/4; k4++) {
        float4 w = W4[k4];
        #pragma unroll
        for (int r = 0; r < 8; r++) {
            float4 sv = *(const float4*)&s_in[r][k4*4];
            acc[r] = fmaf(sv.x, w.x, acc[r]);
            acc[r] = fmaf(sv.y, w.y, acc[r]);
            acc[r] = fmaf(sv.z, w.z, acc[r]);
            acc[r] = fmaf(sv.w, w.w, acc[r]);
        }
    }

    if (z < 2) {
        const int p = d >> 1;
        #pragma unroll
        for (int r = 0; r < 8; r++) {
            float th = emb[(size_t)(n0 + r)*(DM/2) + h*32 + p];
            float cs = cosf(th), sn = sinf(th);
            float partner = __shfl_xor(acc[r], 1);
            // out[2i] = x[2i]*cos - x[2i+1]*sin ; out[2i+1] = x[2i+1]*cos + x[2i]*sin
            acc[r] = (d & 1) ? (acc[r]*cs + partner*sn) : (acc[r]*cs - partner*sn);
            if (z == 0) acc[r] *= 0.125f;   // 1/sqrt(64) folded into Q
        }
    }

    float* dst = ws + (size_t)z*MAT_STRIDE + (size_t)h*HEAD_STRIDE + (size_t)n0*DH + d;
    #pragma unroll
    for (int r = 0; r < 8; r++) dst[r*DH] = acc[r];
}

// ---------------- Kernel 2: scores GEMM (fp32) ----------------
// grid (32, 32, 4), block 256. Writes raw scores into d_out's sparse region.
__global__ __launch_bounds__(256) void scores_kernel(const float* __restrict__ ws, float* __restrict__ sp)
{
    const int h  = blockIdx.z;
    const int m0 = blockIdx.x * 64;   // key index tile
    const int n0 = blockIdx.y * 64;   // query index tile
    __shared__ float Qs[64][68];      // transposed: [d][row], pad 68 keeps 16B align, spreads banks
    __shared__ float Ks[64][68];
    const float* Q = ws + (size_t)h*HEAD_STRIDE;
    const float* K = ws + MAT_STRIDE + (size_t)h*HEAD_STRIDE;
    const int tid = threadIdx.x;
    #pragma unroll
    for (int i = 0; i < 4; i++) {
        int f = tid + 256*i;          // 0..1023 float4s
        int r = f >> 4, d4 = (f & 15) << 2;
        float4 qv = *(const float4*)(Q + (size_t)(n0 + r)*DH + d4);
        float4 kv = *(const float4*)(K + (size_t)(m0 + r)*DH + d4);
        Qs[d4+0][r] = qv.x; Qs[d4+1][r] = qv.y; Qs[d4+2][r] = qv.z; Qs[d4+3][r] = qv.w;
        Ks[d4+0][r] = kv.x; Ks[d4+1][r] = kv.y; Ks[d4+2][r] = kv.z; Ks[d4+3][r] = kv.w;
    }
    __syncthreads();
    const int tx = tid & 15, ty = tid >> 4;
    float acc[4][4];
    #pragma unroll
    for (int i = 0; i < 4; i++)
        #pragma unroll
        for (int j = 0; j < 4; j++) acc[i][j] = 0.f;

    #pragma unroll 8
    for (int d = 0; d < 64; d++) {
        float4 qv = *(const float4*)&Qs[d][ty*4];
        float4 kv = *(const float4*)&Ks[d][tx*4];
        float q[4] = {qv.x, qv.y, qv.z, qv.w};
        float k[4] = {kv.x, kv.y, kv.z, kv.w};
        #pragma unroll
        for (int i = 0; i < 4; i++)
            #pragma unroll
            for (int j = 0; j < 4; j++) acc[i][j] = fmaf(q[i], k[j], acc[i][j]);
    }
    #pragma unroll
    for (int i = 0; i < 4; i++) {
        int row = n0 + ty*4 + i;
        float4 o = make_float4(acc[i][0], acc[i][1], acc[i][2], acc[i][3]);
        *(float4*)(sp + ((size_t)(h*NPTS + row))*NPTS + (m0 + tx*4)) = o;
    }
}

// ---------------- Kernel 3: top-k + softmax + sparse write + hidden ----------------
__device__ inline uint32_t f2u(float f) {
    uint32_t x = __float_as_uint(f);
    return (x & 0x80000000u) ? ~x : (x | 0x80000000u);
}
__device__ inline float u2f(uint32_t u) {
    uint32_t x = (u & 0x80000000u) ? (u ^ 0x80000000u) : ~u;
    return __uint_as_float(x);
}

// grid (256, 4), block 256 (4 waves). Block = 8 query rows of one head.
__global__ __launch_bounds__(256) void topk_attend_kernel(const float* __restrict__ ws, float* __restrict__ out)
{
    const int h  = blockIdx.y;
    const int n0 = blockIdx.x * 8;
    float* sp = out + (size_t)NPTS*DM;           // sparse region (currently raw scores)
    __shared__ float s_s[8][NPTS];               // 64 KB: scores -> probs
    __shared__ float s_hid[4][8][DH];            // 8 KB partials

    // phase 1: stage 8 score rows into LDS
    {
        const float4* src = (const float4*)(sp + ((size_t)(h*NPTS + n0))*NPTS);
        float4* dst = (float4*)&s_s[0][0];
        #pragma unroll
        for (int i = 0; i < 16; i++) {
            int f = threadIdx.x + 256*i;
            dst[f] = src[f];
        }
    }
    __syncthreads();

    const int wave = threadIdx.x >> 6, lane = threadIdx.x & 63;
    // phase 2: per wave, 2 rows: exact 1024-th largest via 32-bit binary search
    for (int rr = 0; rr < 2; rr++) {
        const int row = wave*2 + rr;
        uint32_t u[32];
        #pragma unroll
        for (int j = 0; j < 32; j++) u[j] = f2u(s_s[row][lane + 64*j]);

        uint32_t cur = 0u;
        for (int bit = 31; bit >= 0; bit--) {
            uint32_t cand = cur | (1u << bit);
            int c = 0;
            #pragma unroll
            for (int j = 0; j < 32; j++) c += (u[j] >= cand) ? 1 : 0;
            #pragma unroll
            for (int off = 32; off; off >>= 1) c += __shfl_xor(c, off);
            if (c >= KK) cur = cand;
        }
        // row max
        uint32_t mu = 0u;
        #pragma unroll
        for (int j = 0; j < 32; j++) mu = (u[j] > mu) ? u[j] : mu;
        #pragma unroll
        for (int off = 32; off; off >>= 1) {
            uint32_t o = (uint32_t)__shfl_xor((int)mu, off);
            mu = (o > mu) ? o : mu;
        }
        const float mx = u2f(mu);

        float e[32];
        float zsum = 0.f;
        #pragma unroll
        for (int j = 0; j < 32; j++) {
            bool sel = (u[j] >= cur);
            float f = u2f(u[j]);
            float ev = sel ? expf(f - mx) : 0.f;
            e[j] = ev;
            zsum += ev;
        }
        #pragma unroll
        for (int off = 32; off; off >>= 1) zsum += __shfl_xor(zsum, off);
        const float rz = 1.f / zsum;

        float* gdst = sp + ((size_t)(h*NPTS + n0 + row))*NPTS + lane;
        #pragma unroll
        for (int j = 0; j < 32; j++) {
            float p = e[j] * rz;
            gdst[64*j] = p;                      // coalesced global write (probs / zeros)
            s_s[row][lane + 64*j] = p;           // keep for PV
        }
    }
    __syncthreads();

    // phase 3: hidden = P @ V. thread = (m-chunk, d); loop m outer so V is read once per block
    const int d = threadIdx.x & 63, chunk = threadIdx.x >> 6;
    const float* V = ws + 2*(size_t)MAT_STRIDE + (size_t)h*HEAD_STRIDE;
    float macc[8];
    #pragma unroll
    for (int r = 0; r < 8; r++) macc[r] = 0.f;
    const int mbase = chunk * 512;
    for (int m = mbase; m < mbase + 512; m += 4) {
        float v0 = V[(size_t)(m+0)*DH + d];
        float v1 = V[(size_t)(m+1)*DH + d];
        float v2 = V[(size_t)(m+2)*DH + d];
        float v3 = V[(size_t)(m+3)*DH + d];
        #pragma unroll
        for (int r = 0; r < 8; r++) {
            float4 pv = *(const float4*)&s_s[r][m];   // broadcast read
            macc[r] = fmaf(pv.x, v0, macc[r]);
            macc[r] = fmaf(pv.y, v1, macc[r]);
            macc[r] = fmaf(pv.z, v2, macc[r]);
            macc[r] = fmaf(pv.w, v3, macc[r]);
        }
    }
    #pragma unroll
    for (int r = 0; r < 8; r++) s_hid[chunk][r][d] = macc[r];
    __syncthreads();
    #pragma unroll
    for (int i = 0; i < 2; i++) {
        int idx = threadIdx.x + 256*i;               // 0..511
        int r = idx >> 6, dd = idx & 63;
        float s = s_hid[0][r][dd] + s_hid[1][r][dd] + s_hid[2][r][dd] + s_hid[3][r][dd];
        out[(size_t)(n0 + r)*DM + h*DH + dd] = s;    // hidden[n][h*64+d]
    }
}

extern "C" void kernel_launch(void* const* d_in, const int* in_sizes, int n_in,
                              void* d_out, int out_size, void* d_ws, size_t ws_size,
                              hipStream_t stream)
{
    const float* xq  = (const float*)d_in[0];
    const float* xk  = (const float*)d_in[1];
    const float* xv  = (const float*)d_in[2];
    const float* emb = (const float*)d_in[3];
    const float* Wq  = (const float*)d_in[4];
    const float* bq  = (const float*)d_in[5];
    const float* Wk  = (const float*)d_in[6];
    const float* bk  = (const float*)d_in[7];
    const float* Wv  = (const float*)d_in[8];
    const float* bv  = (const float*)d_in[9];
    // d_in[10] = layer (always 0, K_LIST[0]=0.5 -> KK=1024, hard-coded)
    float* out = (float*)d_out;
    float* ws  = (float*)d_ws;   // needs 6 MB for Q,K,V

    proj_rope_kernel<<<dim3(NPTS/8, 3), 256, 0, stream>>>(xq, xk, xv, emb, Wq, bq, Wk, bk, Wv, bv, ws);
    scores_kernel<<<dim3(NPTS/64, NPTS/64, NH), 256, 0, stream>>>(ws, out + (size_t)NPTS*DM);
    topk_attend_kernel<<<dim3(NPTS/8, NH), 256, 0, stream>>>(ws, out);
}

// Round 2
// 135.337 us; speedup vs baseline: 1.4462x; 1.4462x over previous
//
#include <hip/hip_runtime.h>
#include <hip/hip_bf16.h>
#include <stdint.h>

#define NPTS 2048
#define DM 256
#define NH 4
#define DH 64
#define KK 1024

// ws layout (floats): Q[4][2048][64] | K[4][2048][64] | V[4][2048][64]
#define HEAD_STRIDE (NPTS*DH)     // 131072
#define MAT_STRIDE  (NH*NPTS*DH)  // 524288

// ---------------- Kernel 1: projections + rotary ----------------
// grid (256, 3), block 256. z: 0=Q(rotary+scale), 1=K(rotary), 2=V
__global__ __launch_bounds__(256) void proj_rope_kernel(
    const float* __restrict__ xq, const float* __restrict__ xk, const float* __restrict__ xv,
    const float* __restrict__ emb,
    const float* __restrict__ Wq, const float* __restrict__ bq,
    const float* __restrict__ Wk, const float* __restrict__ bk,
    const float* __restrict__ Wv, const float* __restrict__ bv,
    float* __restrict__ ws)
{
    const int z = blockIdx.y;
    const int n0 = blockIdx.x * 8;
    const float* X = (z==0) ? xq : (z==1) ? xk : xv;
    const float* W = (z==0) ? Wq : (z==1) ? Wk : Wv;
    const float* B = (z==0) ? bq : (z==1) ? bk : bv;

    __shared__ float s_in[8][DM];
    {
        const float4* X4 = (const float4*)(X + (size_t)n0 * DM);
        float4* s4 = (float4*)&s_in[0][0];
        #pragma unroll
        for (int i = 0; i < 2; i++) {
            int f = threadIdx.x + 256*i;
            s4[f] = X4[f];
        }
    }
    __syncthreads();

    const int c = threadIdx.x;
    const int h = c >> 6, d = c & 63;
    const float bias = B[c];
    float acc[8];
    #pragma unroll
    for (int r = 0; r < 8; r++) acc[r] = bias;

    const float4* W4 = (const float4*)(W + (size_t)c * DM);
    #pragma unroll 4
    for (int k4 = 0; k4 < DM/4; k4++) {
        float4 w = W4[k4];
        #pragma unroll
        for (int r = 0; r < 8; r++) {
            float4 sv = *(const float4*)&s_in[r][k4*4];
            acc[r] = fmaf(sv.x, w.x, acc[r]);
            acc[r] = fmaf(sv.y, w.y, acc[r]);
            acc[r] = fmaf(sv.z, w.z, acc[r]);
            acc[r] = fmaf(sv.w, w.w, acc[r]);
        }
    }

    if (z < 2) {
        const int p = d >> 1;
        #pragma unroll
        for (int r = 0; r < 8; r++) {
            float th = emb[(size_t)(n0 + r)*(DM/2) + h*32 + p];
            float cs = cosf(th), sn = sinf(th);
            float partner = __shfl_xor(acc[r], 1);
            acc[r] = (d & 1) ? (acc[r]*cs + partner*sn) : (acc[r]*cs - partner*sn);
            if (z == 0) acc[r] *= 0.125f;   // 1/sqrt(64) folded into Q
        }
    }

    float* dst = ws + (size_t)z*MAT_STRIDE + (size_t)h*HEAD_STRIDE + (size_t)n0*DH + d;
    #pragma unroll
    for (int r = 0; r < 8; r++) dst[r*DH] = acc[r];
}

// ---------------- Kernel 2: scores GEMM (fp32) ----------------
// grid (32, 32, 4), block 256. Writes raw scores into d_out's sparse region.
__global__ __launch_bounds__(256) void scores_kernel(const float* __restrict__ ws, float* __restrict__ sp)
{
    const int h  = blockIdx.z;
    const int m0 = blockIdx.x * 64;   // key index tile
    const int n0 = blockIdx.y * 64;   // query index tile
    __shared__ float Qs[64][68];
    __shared__ float Ks[64][68];
    const float* Q = ws + (size_t)h*HEAD_STRIDE;
    const float* K = ws + MAT_STRIDE + (size_t)h*HEAD_STRIDE;
    const int tid = threadIdx.x;
    #pragma unroll
    for (int i = 0; i < 4; i++) {
        int f = tid + 256*i;
        int r = f >> 4, d4 = (f & 15) << 2;
        float4 qv = *(const float4*)(Q + (size_t)(n0 + r)*DH + d4);
        float4 kv = *(const float4*)(K + (size_t)(m0 + r)*DH + d4);
        Qs[d4+0][r] = qv.x; Qs[d4+1][r] = qv.y; Qs[d4+2][r] = qv.z; Qs[d4+3][r] = qv.w;
        Ks[d4+0][r] = kv.x; Ks[d4+1][r] = kv.y; Ks[d4+2][r] = kv.z; Ks[d4+3][r] = kv.w;
    }
    __syncthreads();
    const int tx = tid & 15, ty = tid >> 4;
    float acc[4][4];
    #pragma unroll
    for (int i = 0; i < 4; i++)
        #pragma unroll
        for (int j = 0; j < 4; j++) acc[i][j] = 0.f;

    #pragma unroll 8
    for (int d = 0; d < 64; d++) {
        float4 qv = *(const float4*)&Qs[d][ty*4];
        float4 kv = *(const float4*)&Ks[d][tx*4];
        float q[4] = {qv.x, qv.y, qv.z, qv.w};
        float k[4] = {kv.x, kv.y, kv.z, kv.w};
        #pragma unroll
        for (int i = 0; i < 4; i++)
            #pragma unroll
            for (int j = 0; j < 4; j++) acc[i][j] = fmaf(q[i], k[j], acc[i][j]);
    }
    #pragma unroll
    for (int i = 0; i < 4; i++) {
        int row = n0 + ty*4 + i;
        float4 o = make_float4(acc[i][0], acc[i][1], acc[i][2], acc[i][3]);
        *(float4*)(sp + ((size_t)(h*NPTS + row))*NPTS + (m0 + tx*4)) = o;
    }
}

// ---------------- Kernel 3: top-k + softmax + sparse write + hidden ----------------
__device__ inline uint32_t f2u(float f) {
    uint32_t x = __float_as_uint(f);
    return (x & 0x80000000u) ? ~x : (x | 0x80000000u);
}
__device__ inline float u2f(uint32_t u) {
    uint32_t x = (u & 0x80000000u) ? (u ^ 0x80000000u) : ~u;
    return __uint_as_float(x);
}

// grid (256, 4), block 512 (8 waves). Block = 8 query rows of one head, 1 row/wave.
__global__ __launch_bounds__(512, 4) void topk_attend_kernel(const float* __restrict__ ws, float* __restrict__ out)
{
    const int h  = blockIdx.y;
    const int n0 = blockIdx.x * 8;
    float* sp = out + (size_t)NPTS*DM;           // sparse region (raw scores on entry)
    __shared__ float s_s[8][NPTS];               // 64 KB: probs for PV
    __shared__ float s_hid[8][8][DH];            // 16 KB partials

    const int wave = threadIdx.x >> 6, lane = threadIdx.x & 63;
    const int row = wave;                        // one row per wave

    // phase 1: load this row's 2048 scores straight to registers (float4, coalesced).
    // register slot (j,i) holds m = 4*(lane+64*j)+i — selection is order-agnostic.
    float* grow = sp + ((size_t)(h*NPTS + n0 + row))*NPTS;
    uint32_t u[32];
    #pragma unroll
    for (int j = 0; j < 8; j++) {
        float4 v = ((const float4*)grow)[lane + 64*j];
        u[4*j+0] = f2u(v.x); u[4*j+1] = f2u(v.y); u[4*j+2] = f2u(v.z); u[4*j+3] = f2u(v.w);
    }

    // row max (once; shuffle tree is fine here)
    uint32_t mu = 0u;
    #pragma unroll
    for (int j = 0; j < 32; j++) mu = (u[j] > mu) ? u[j] : mu;
    #pragma unroll
    for (int off = 32; off; off >>= 1) {
        uint32_t o = (uint32_t)__shfl_xor((int)mu, off);
        mu = (o > mu) ? o : mu;
    }
    const float mx = u2f(mu);

    // phase 2: exact 1024-th largest via binary search with ballot+popcount counting.
    // count is wave-uniform -> uniform branch, early exit when count == KK exactly.
    uint32_t cur = 0u;
    for (int bit = 31; bit >= 0; bit--) {
        uint32_t cand = cur | (1u << bit);
        int c = 0;
        #pragma unroll
        for (int j = 0; j < 32; j++) c += (int)__popcll(__ballot(u[j] >= cand));
        if (c >= KK) { cur = cand; if (c == KK) break; }
    }

    // softmax over selected; exp results overwrite u[] (no extra VGPRs)
    float zsum = 0.f;
    #pragma unroll
    for (int j = 0; j < 32; j++) {
        bool sel = (u[j] >= cur);
        float f = u2f(u[j]);
        float ev = sel ? __expf(f - mx) : 0.f;
        u[j] = __float_as_uint(ev);
        zsum += ev;
    }
    #pragma unroll
    for (int off = 32; off; off >>= 1) zsum += __shfl_xor(zsum, off);
    const float rz = 1.f / zsum;

    // write probs: global (dense row, overwrites raw scores) + LDS for PV
    #pragma unroll
    for (int j = 0; j < 8; j++) {
        float4 p;
        p.x = __uint_as_float(u[4*j+0]) * rz;
        p.y = __uint_as_float(u[4*j+1]) * rz;
        p.z = __uint_as_float(u[4*j+2]) * rz;
        p.w = __uint_as_float(u[4*j+3]) * rz;
        ((float4*)grow)[lane + 64*j] = p;
        ((float4*)&s_s[row][0])[lane + 64*j] = p;
    }
    __syncthreads();

    // phase 3: hidden = P @ V. wave = m-chunk (256 m's), lane = d.
    const int d = lane;
    const float* V = ws + 2*(size_t)MAT_STRIDE + (size_t)h*HEAD_STRIDE;
    float macc[8];
    #pragma unroll
    for (int r = 0; r < 8; r++) macc[r] = 0.f;
    const int mbase = wave * 256;
    for (int m = mbase; m < mbase + 256; m += 4) {
        float v0 = V[(size_t)(m+0)*DH + d];
        float v1 = V[(size_t)(m+1)*DH + d];
        float v2 = V[(size_t)(m+2)*DH + d];
        float v3 = V[(size_t)(m+3)*DH + d];
        #pragma unroll
        for (int r = 0; r < 8; r++) {
            float4 pv = *(const float4*)&s_s[r][m];   // wave-uniform addr -> broadcast
            macc[r] = fmaf(pv.x, v0, macc[r]);
            macc[r] = fmaf(pv.y, v1, macc[r]);
            macc[r] = fmaf(pv.z, v2, macc[r]);
            macc[r] = fmaf(pv.w, v3, macc[r]);
        }
    }
    #pragma unroll
    for (int r = 0; r < 8; r++) s_hid[wave][r][d] = macc[r];
    __syncthreads();

    {
        int idx = threadIdx.x;                        // 0..511 = 8 rows x 64 d
        int r = idx >> 6, dd = idx & 63;
        float s = 0.f;
        #pragma unroll
        for (int c2 = 0; c2 < 8; c2++) s += s_hid[c2][r][dd];
        out[(size_t)(n0 + r)*DM + h*DH + dd] = s;     // hidden[n][h*64+d]
    }
}

extern "C" void kernel_launch(void* const* d_in, const int* in_sizes, int n_in,
                              void* d_out, int out_size, void* d_ws, size_t ws_size,
                              hipStream_t stream)
{
    const float* xq  = (const float*)d_in[0];
    const float* xk  = (const float*)d_in[1];
    const float* xv  = (const float*)d_in[2];
    const float* emb = (const float*)d_in[3];
    const float* Wq  = (const float*)d_in[4];
    const float* bq  = (const float*)d_in[5];
    const float* Wk  = (const float*)d_in[6];
    const float* bk  = (const float*)d_in[7];
    const float* Wv  = (const float*)d_in[8];
    const float* bv  = (const float*)d_in[9];
    float* out = (float*)d_out;
    float* ws  = (float*)d_ws;   // needs 6 MB for Q,K,V

    proj_rope_kernel<<<dim3(NPTS/8, 3), 256, 0, stream>>>(xq, xk, xv, emb, Wq, bq, Wk, bk, Wv, bv, ws);
    scores_kernel<<<dim3(NPTS/64, NPTS/64, NH), 256, 0, stream>>>(ws, out + (size_t)NPTS*DM);
    topk_attend_kernel<<<dim3(NPTS/8, NH), 512, 0, stream>>>(ws, out);
}